// Round 21
// baseline (126.374 us; speedup 1.0000x reference)
//
#include <hip/hip_runtime.h>
#include <hip/hip_bf16.h>

// Shapes: B=2, L=2048, D_IN=1024, D_OUT=1024, H=16, HD=64
// Pipeline:
//   cvt_all: per-section blocks (r20, ~10us)
//   proj:   ROUND 21: 64x64 tiles (VGPR ~56 <= 64 -> 8 waves/SIMD possible; 4096 blocks,
//           LDS 16KB -> 8 resident blocks/CU = ~32 waves/CU, 4x r20's occupancy).
//           QGK: 64x48 tiles; VT: 16x64. K-order unchanged -> bit-identical numerics.
//           r13-r17 evidence: proj insensitive to staging schedule; VGPR=68 wave cap
//           was the binding constraint. Occupancy via NATURAL tile size (r15/r18 lesson).
//   attn:   flash attention (byte-identical r12-r20: deterministic 0.00390625, ~29us)
//   gemm_out: out = ctx @ Wo^T + bo, 64x64 tiles, 1024 blocks (byte-identical r18-r20)

typedef __bf16 v8bf __attribute__((ext_vector_type(8)));
typedef __bf16 v4bf __attribute__((ext_vector_type(4)));
typedef float  v4f  __attribute__((ext_vector_type(4)));

using gas_void = const __attribute__((address_space(1))) void*;
using las_void = __attribute__((address_space(3))) void*;

__device__ __forceinline__ void async_ld16(const void* g, void* l) {
  __builtin_amdgcn_global_load_lds((gas_void)g, (las_void)l, 16, 0, 0);
}
__device__ __forceinline__ float fexp2(float x) { return __builtin_amdgcn_exp2f(x); }

#define QSCALE 0.18033688011112042f  /* 0.125 * log2(e) */
#define LOG2E  1.4426950408889634f
#define FIXMAX 8.0f                   /* fixed softmax max in exp2 domain */

// ---------------- all fp32 -> bf16 conversions, one section per block ----------------
__global__ void cvt_all_kernel(const float* __restrict__ x,  const float* __restrict__ Wq,
                               const float* __restrict__ Wg, const float* __restrict__ Wk,
                               const float* __restrict__ Wv, const float* __restrict__ Wo,
                               __bf16* __restrict__ xb, __bf16* __restrict__ w3,
                               __bf16* __restrict__ wvb, __bf16* __restrict__ wob) {
  const int bid = blockIdx.x;
  const float* s; v4bf* d; int j0; float sc = 1.f;
  if (bid < 2048) {
    s = x; d = (v4bf*)xb; j0 = bid * 512;
  } else {
    const int g   = (bid - 2048) >> 9;
    const int off = ((bid - 2048) & 511) * 512;
    if (g == 0)      { s = Wq; d = (v4bf*)w3;           sc = QSCALE; }
    else if (g == 1) { s = Wg; d = (v4bf*)w3 + 262144; }
    else if (g == 2) { s = Wk; d = (v4bf*)w3 + 524288; }
    else if (g == 3) { s = Wv; d = (v4bf*)wvb; }
    else             { s = Wo; d = (v4bf*)wob; }
    j0 = off;
  }
  const int j1 = j0 + threadIdx.x;
  const int j2 = j1 + 256;
  float4 v1 = reinterpret_cast<const float4*>(s)[j1];
  float4 v2 = reinterpret_cast<const float4*>(s)[j2];
  v4bf o1, o2;
  o1[0] = (__bf16)(v1.x * sc); o1[1] = (__bf16)(v1.y * sc);
  o1[2] = (__bf16)(v1.z * sc); o1[3] = (__bf16)(v1.w * sc);
  o2[0] = (__bf16)(v2.x * sc); o2[1] = (__bf16)(v2.y * sc);
  o2[2] = (__bf16)(v2.z * sc); o2[3] = (__bf16)(v2.w * sc);
  d[j1] = o1;
  d[j2] = o2;
}

// ---------------- 64x64 bf16 B^T GEMM tile, single-buf BK=64, XOR swizzle ----------------
// C[m0:m0+64, n0:n0+64] = A[m0:,:K] * B[n0:,:K]^T ; per-wave 32x32 (acc 2x2 = 16 AGPR).
template<bool OUTF32>
__device__ __forceinline__ void tile64(
    const __bf16* __restrict__ A, const __bf16* __restrict__ B,
    void* __restrict__ C, const float* __restrict__ bias,
    int K, int lda, int ldb, int ldc, int m0, int n0,
    __bf16* As, __bf16* Bs) {
  const int tid  = threadIdx.x;
  const int w    = tid >> 6;
  const int lane = tid & 63;
  const int fr   = lane & 15;
  const int fq   = lane >> 4;
  const int sr   = lane >> 3;
  const int sc   = lane & 7;
  const int wr = (w >> 1) * 32, wc = (w & 1) * 32;

  v4f acc[2][2];
#pragma unroll
  for (int i = 0; i < 2; ++i)
#pragma unroll
    for (int j = 0; j < 2; ++j)
#pragma unroll
      for (int r = 0; r < 4; ++r) acc[i][j][r] = 0.f;

  for (int k0 = 0; k0 < K; k0 += 64) {
#pragma unroll
    for (int i = 0; i < 2; ++i) {
      const int c = w + i * 4;  // 8 chunks of 8 rows per matrix
      async_ld16(A + (size_t)(m0 + c * 8 + sr) * lda + k0 + ((sc ^ sr) * 8),
                 (void*)(As + c * 512));
      async_ld16(B + (size_t)(n0 + c * 8 + sr) * ldb + k0 + ((sc ^ sr) * 8),
                 (void*)(Bs + c * 512));
    }
    __syncthreads();

#pragma unroll
    for (int ks = 0; ks < 2; ++ks) {
      v8bf a[2], b[2];
#pragma unroll
      for (int mi = 0; mi < 2; ++mi)
        a[mi] = *reinterpret_cast<const v8bf*>(
            As + (wr + mi * 16 + fr) * 64 + (((ks * 4 + fq) ^ (fr & 7)) * 8));
#pragma unroll
      for (int ni = 0; ni < 2; ++ni)
        b[ni] = *reinterpret_cast<const v8bf*>(
            Bs + (wc + ni * 16 + fr) * 64 + (((ks * 4 + fq) ^ (fr & 7)) * 8));
      __builtin_amdgcn_s_setprio(1);
#pragma unroll
      for (int mi = 0; mi < 2; ++mi)
#pragma unroll
        for (int ni = 0; ni < 2; ++ni)
          acc[mi][ni] = __builtin_amdgcn_mfma_f32_16x16x32_bf16(a[mi], b[ni], acc[mi][ni], 0, 0, 0);
      __builtin_amdgcn_s_setprio(0);
    }
    __syncthreads();
  }

#pragma unroll
  for (int mi = 0; mi < 2; ++mi)
#pragma unroll
    for (int ni = 0; ni < 2; ++ni)
#pragma unroll
      for (int r = 0; r < 4; ++r) {
        const int row = m0 + wr + mi * 16 + fq * 4 + r;
        const int col = n0 + wc + ni * 16 + fr;
        const float v = acc[mi][ni][r];
        if (OUTF32) {
          reinterpret_cast<float*>(C)[(size_t)row * ldc + col] = v + bias[col];
        } else {
          reinterpret_cast<__bf16*>(C)[(size_t)row * ldc + col] = (__bf16)v;
        }
      }
}

// merged projection, 64x64 tiles: blocks 0..3071 -> QGK (64m x 48n);
// 3072..4095 -> VT (16m x 64n).  LDS 16KB; VGPR ~56 -> up to 8 blocks/CU resident.
__global__ __launch_bounds__(256) void proj_kernel(
    const __bf16* __restrict__ xb, const __bf16* __restrict__ w3,
    const __bf16* __restrict__ wvb, __bf16* __restrict__ qgk, __bf16* __restrict__ vt) {
  __shared__ __bf16 As[64 * 64];
  __shared__ __bf16 Bs[64 * 64];
  const int bid = blockIdx.x;
  if (bid < 3072) {
    tile64<false>(xb, w3, (void*)qgk, nullptr, 1024, 1024, 1024, 3072,
                  (bid / 48) * 64, (bid % 48) * 64, As, Bs);
  } else {
    const int t = bid - 3072;
    tile64<false>(wvb, xb, (void*)vt, nullptr, 1024, 1024, 1024, 4096,
                  (t >> 6) * 64, (t & 63) * 64, As, Bs);
  }
}

// ---------------- out-GEMM: 64x64 tiles (byte-identical to r18-r20) ----------------
__global__ __launch_bounds__(256) void gemm_out_kernel(
    const __bf16* __restrict__ A, const __bf16* __restrict__ B,
    float* __restrict__ C, const float* __restrict__ bias) {
  __shared__ __bf16 As[64 * 64];
  __shared__ __bf16 Bs[64 * 64];
  tile64<true>(A, B, (void*)C, bias, 1024, 1024, 1024, 1024,
               blockIdx.y * 64, blockIdx.x * 64, As, Bs);
}

// ---------------- flash attention: 4-wave blocks, K in LDS, V in regs ----------------
// (byte-identical to rounds 12-20 — deterministic, absmax 0.0039, steady ~29 us)
__global__ __launch_bounds__(256, 4) void attn_kernel(
    const __bf16* __restrict__ QGK, const __bf16* __restrict__ VT,
    __bf16* __restrict__ CTX) {
  constexpr int LD = 3072, L = 2048;
  __shared__ __align__(16) char lds[37888];
  const int w = threadIdx.x >> 6, lane = threadIdx.x & 63;
  const int fr = lane & 15, fq = lane >> 4;
  const int tl = w >> 1, hf = w & 1;
  const int u = blockIdx.x >> 8, v = blockIdx.x & 255;
  const int k = v >> 5;
  const int g = (u == 0) ? k : (u == 1) ? 15 - k : (u == 2) ? 16 + k : 31 - k;
  const int bh = v & 31;
  const int b = bh >> 4, h = bh & 15, hb = h * 64;
  const int qt = 2 * g + tl, q0 = qt * 32, nkt = g + 1;
  const __bf16* base  = QGK + (size_t)b * L * LD;
  const __bf16* vbase = VT + (size_t)hb * 4096 + (size_t)b * L;
  __bf16* pw = (__bf16*)(lds + 16384 + w * 2560);

  v8bf onev;
#pragma unroll
  for (int i = 0; i < 8; ++i) onev[i] = (__bf16)1.0f;

  v8bf qf[2][2];
#pragma unroll
  for (int mi = 0; mi < 2; ++mi)
#pragma unroll
    for (int ks = 0; ks < 2; ++ks)
      qf[mi][ks] = *reinterpret_cast<const v8bf*>(
          base + (size_t)(q0 + mi * 16 + fr) * LD + hb + ks * 32 + fq * 8);

  v4f cacc[2][4], csum[2];
#pragma unroll
  for (int mi = 0; mi < 2; ++mi) {
#pragma unroll
    for (int r = 0; r < 4; ++r) csum[mi][r] = 0.f;
#pragma unroll
    for (int nf = 0; nf < 4; ++nf)
#pragma unroll
      for (int r = 0; r < 4; ++r) cacc[mi][nf][r] = 0.f;
  }

  auto stage = [&](int bi, int k0s) {
    char* bf_ = (char*)lds + bi * 8192;
#pragma unroll
    for (int i = 0; i < 2; ++i) {
      const int slot = i * 256 + w * 64 + lane;
      const int r = slot >> 3;
      const int cc = ((slot & 7) ^ (r & 7)) * 8;
      async_ld16(base + (size_t)(k0s + r) * LD + 2048 + hb + cc,
                 bf_ + (i * 256 + w * 64) * 16);
    }
  };

  stage(0, 0);
  __syncthreads();
  for (int kt = 0; kt < nkt; ++kt) {
    const int k0 = kt * 64;
    const bool last = (kt == nkt - 1);
    v8bf vf[4];
#pragma unroll
    for (int nf = 0; nf < 4; ++nf)
      vf[nf] = *reinterpret_cast<const v8bf*>(
          vbase + (size_t)(nf * 16 + fr) * 4096 + k0 + hf * 32 + fq * 8);
    if (!last) stage((kt + 1) & 1, k0 + 64);

    if (!(last && tl == 0 && hf == 1)) {
      const __bf16* Kt = (const __bf16*)(lds + (kt & 1) * 8192);
      v8bf kf[2][2];
#pragma unroll
      for (int ks = 0; ks < 2; ++ks)
#pragma unroll
        for (int nj = 0; nj < 2; ++nj)
          kf[ks][nj] = *reinterpret_cast<const v8bf*>(
              Kt + (hf * 32 + nj * 16 + fr) * 64 + (((ks * 4 + fq) ^ (fr & 7)) * 8));

      v4f s[2][2];
#pragma unroll
      for (int mi = 0; mi < 2; ++mi)
#pragma unroll
        for (int nj = 0; nj < 2; ++nj)
#pragma unroll
          for (int r = 0; r < 4; ++r) s[mi][nj][r] = 0.f;
      __builtin_amdgcn_s_setprio(1);
#pragma unroll
      for (int ks = 0; ks < 2; ++ks)
#pragma unroll
        for (int mi = 0; mi < 2; ++mi)
#pragma unroll
          for (int nj = 0; nj < 2; ++nj)
            s[mi][nj] = __builtin_amdgcn_mfma_f32_16x16x32_bf16(
                kf[ks][nj], qf[mi][ks], s[mi][nj], 0, 0, 0);
      __builtin_amdgcn_s_setprio(0);

      const bool mask = last && (hf == tl);
#pragma unroll
      for (int mi = 0; mi < 2; ++mi) {
        const int qrow = q0 + mi * 16 + fr;
#pragma unroll
        for (int nj = 0; nj < 2; ++nj) {
          const int kvb = k0 + hf * 32 + nj * 16 + fq * 4;
          v4bf pk;
#pragma unroll
          for (int r = 0; r < 4; ++r) {
            float sv = s[mi][nj][r];
            if (mask && (kvb + r > qrow)) sv = -__builtin_inff();
            pk[r] = (__bf16)fexp2(sv - FIXMAX);
          }
          *reinterpret_cast<v4bf*>(pw + (mi * 16 + fr) * 40 + nj * 16 + fq * 4) = pk;
        }
      }

      v8bf pa[2];
#pragma unroll
      for (int mi = 0; mi < 2; ++mi)
        pa[mi] = *reinterpret_cast<const v8bf*>(pw + (mi * 16 + fr) * 40 + fq * 8);
      __builtin_amdgcn_s_setprio(1);
#pragma unroll
      for (int mi = 0; mi < 2; ++mi)
        csum[mi] = __builtin_amdgcn_mfma_f32_16x16x32_bf16(pa[mi], onev, csum[mi], 0, 0, 0);
#pragma unroll
      for (int nf = 0; nf < 4; ++nf)
#pragma unroll
        for (int mi = 0; mi < 2; ++mi)
          cacc[mi][nf] = __builtin_amdgcn_mfma_f32_16x16x32_bf16(pa[mi], vf[nf], cacc[mi][nf], 0, 0, 0);
      __builtin_amdgcn_s_setprio(0);
    }
    __syncthreads();
  }

  float* comb = (float*)(lds + 16384);
  float* slot = comb + (tl * 64 + lane) * 41;
  if (hf == 1) {
#pragma unroll
    for (int mi = 0; mi < 2; ++mi) {
#pragma unroll
      for (int nf = 0; nf < 4; ++nf)
#pragma unroll
        for (int r = 0; r < 4; ++r) slot[mi * 16 + nf * 4 + r] = cacc[mi][nf][r];
#pragma unroll
      for (int r = 0; r < 4; ++r) slot[32 + mi * 4 + r] = csum[mi][r];
    }
  }
  __syncthreads();
  if (hf == 0) {
#pragma unroll
    for (int mi = 0; mi < 2; ++mi) {
#pragma unroll
      for (int nf = 0; nf < 4; ++nf)
#pragma unroll
        for (int r = 0; r < 4; ++r) cacc[mi][nf][r] += slot[mi * 16 + nf * 4 + r];
#pragma unroll
      for (int r = 0; r < 4; ++r) csum[mi][r] += slot[32 + mi * 4 + r];
    }
#pragma unroll
    for (int mi = 0; mi < 2; ++mi)
#pragma unroll
      for (int r = 0; r < 4; ++r) {
        const int grow = q0 + mi * 16 + fq * 4 + r;
        const float rl = 1.f / csum[mi][r];
#pragma unroll
        for (int nf = 0; nf < 4; ++nf) {
          const int col = hb + nf * 16 + fr;
          float vv = cacc[mi][nf][r] * rl;
          const float gt = (float)base[(size_t)grow * LD + 1024 + col];
          vv *= 1.f / (1.f + fexp2(-gt * LOG2E));
          CTX[((size_t)b * L + grow) * 1024 + col] = (__bf16)vv;
        }
      }
  }
}

extern "C" void kernel_launch(void* const* d_in, const int* in_sizes, int n_in,
                              void* d_out, int out_size, void* d_ws, size_t ws_size,
                              hipStream_t stream) {
  const float* x  = (const float*)d_in[0];
  const float* Wq = (const float*)d_in[1];
  const float* Wg = (const float*)d_in[2];
  const float* Wk = (const float*)d_in[3];
  const float* Wv = (const float*)d_in[4];
  const float* Wo = (const float*)d_in[5];
  const float* bo = (const float*)d_in[6];

  char* ws = (char*)d_ws;
  __bf16* xb  = (__bf16*)(ws);                  //  8 MB  [4096,1024]
  __bf16* w3  = (__bf16*)(ws + (8u  << 20));    //  6 MB  [3072,1024]
  __bf16* wvb = (__bf16*)(ws + (14u << 20));    //  2 MB
  __bf16* wob = (__bf16*)(ws + (16u << 20));    //  2 MB
  __bf16* qgk = (__bf16*)(ws + (18u << 20));    // 24 MB  [4096,3072]
  __bf16* vt  = (__bf16*)(ws + (42u << 20));    //  8 MB  [1024,4096]
  __bf16* ctx = (__bf16*)(ws + (50u << 20));    //  8 MB  [4096,1024]

  cvt_all_kernel<<<dim3(4608), dim3(256), 0, stream>>>(x, Wq, Wg, Wk, Wv, Wo,
                                                       xb, w3, wvb, wob);

  // QGK (3072 blocks) + VT (1024 blocks) in one dispatch; 64x64 tiles, full occupancy
  proj_kernel<<<dim3(4096), dim3(256), 0, stream>>>(xb, w3, wvb, qgk, vt);

  // flash attention + gate: 1024 blocks = exact residency (4/CU)
  attn_kernel<<<dim3(1024), dim3(256), 0, stream>>>(qgk, vt, ctx);

  // out = ctx @ Wo^T + bo : 64x64 tiles -> 1024 blocks (4/CU)
  gemm_out_kernel<<<dim3(16, 64), dim3(256), 0, stream>>>(ctx, wob, (float*)d_out, bo);
}

// Round 22
// 119.241 us; speedup vs baseline: 1.0598x; 1.0598x over previous
//
#include <hip/hip_runtime.h>
#include <hip/hip_bf16.h>

// Shapes: B=2, L=2048, D_IN=1024, D_OUT=1024, H=16, HD=64
// Pipeline (best-known composition):
//   cvt_all: per-section blocks + 16B stores (2 adjacent f4 -> 1 v8bf per thread)
//   proj:   128x64 dbuf counted-vmcnt tiles (r17/r20 best: 55.3us, deterministic)
//   attn:   flash attention (byte-identical r12-r21: deterministic 0.00390625, ~29us)
//   gemm_out: 64x64 tiles, 1024 blocks (byte-identical r18-r21, ~14us)
// Plateau evidence: proj insensitive to staging (r13-r17), occupancy (r14/r21);
// all MFMA kernels at ~600 TF = 2-barrier structural ceiling at K=1024 shapes.

typedef __bf16 v8bf __attribute__((ext_vector_type(8)));
typedef __bf16 v4bf __attribute__((ext_vector_type(4)));
typedef float  v4f  __attribute__((ext_vector_type(4)));

using gas_void = const __attribute__((address_space(1))) void*;
using las_void = __attribute__((address_space(3))) void*;

__device__ __forceinline__ void async_ld16(const void* g, void* l) {
  __builtin_amdgcn_global_load_lds((gas_void)g, (las_void)l, 16, 0, 0);
}
__device__ __forceinline__ float fexp2(float x) { return __builtin_amdgcn_exp2f(x); }

#define QSCALE 0.18033688011112042f  /* 0.125 * log2(e) */
#define LOG2E  1.4426950408889634f
#define FIXMAX 8.0f                   /* fixed softmax max in exp2 domain */

// ------- all fp32 -> bf16 conversions: one section per block, 16B stores -------
// Blocks 0..2047: x. Blocks 2048+: 512-block groups for Wq,Wg,Wk,Wv,Wo.
// Thread t: f4 indices j0+2t, j0+2t+1 (32B contiguous load) -> one v8bf store (16B).
__global__ void cvt_all_kernel(const float* __restrict__ x,  const float* __restrict__ Wq,
                               const float* __restrict__ Wg, const float* __restrict__ Wk,
                               const float* __restrict__ Wv, const float* __restrict__ Wo,
                               __bf16* __restrict__ xb, __bf16* __restrict__ w3,
                               __bf16* __restrict__ wvb, __bf16* __restrict__ wob) {
  const int bid = blockIdx.x;
  const float* s; v4bf* d; int j0; float sc = 1.f;
  if (bid < 2048) {
    s = x; d = (v4bf*)xb; j0 = bid * 512;
  } else {
    const int g   = (bid - 2048) >> 9;
    const int off = ((bid - 2048) & 511) * 512;
    if (g == 0)      { s = Wq; d = (v4bf*)w3;           sc = QSCALE; }
    else if (g == 1) { s = Wg; d = (v4bf*)w3 + 262144; }
    else if (g == 2) { s = Wk; d = (v4bf*)w3 + 524288; }
    else if (g == 3) { s = Wv; d = (v4bf*)wvb; }
    else             { s = Wo; d = (v4bf*)wob; }
    j0 = off;
  }
  const int j = j0 + threadIdx.x * 2;  // even -> 16B-aligned destination
  float4 v1 = reinterpret_cast<const float4*>(s)[j];
  float4 v2 = reinterpret_cast<const float4*>(s)[j + 1];
  v8bf o;
  o[0] = (__bf16)(v1.x * sc); o[1] = (__bf16)(v1.y * sc);
  o[2] = (__bf16)(v1.z * sc); o[3] = (__bf16)(v1.w * sc);
  o[4] = (__bf16)(v2.x * sc); o[5] = (__bf16)(v2.y * sc);
  o[6] = (__bf16)(v2.z * sc); o[7] = (__bf16)(v2.w * sc);
  *reinterpret_cast<v8bf*>(d + j) = o;
}

// ---------------- bf16 B^T GEMM tile: BK=64 dbuf, XOR swizzle, counted vmcnt ----------------
// (byte-identical to r17/r20 -- deterministic)
template<bool OUTF32, int BN>
__device__ __forceinline__ void gemm_tile(
    const __bf16* __restrict__ A, const __bf16* __restrict__ B,
    void* __restrict__ C, const float* __restrict__ bias,
    int K, int lda, int ldb, int ldc, int m0, int n0,
    __bf16* As, __bf16* Bs) {
  constexpr int NI = BN / 32;
  const int tid  = threadIdx.x;
  const int w    = tid >> 6;
  const int lane = tid & 63;
  const int fr   = lane & 15;
  const int fq   = lane >> 4;
  const int sr   = lane >> 3;
  const int sc   = lane & 7;
  const int wr = (w >> 1) * 64, wc = (w & 1) * (BN / 2);

  v4f acc[4][NI];
#pragma unroll
  for (int i = 0; i < 4; ++i)
#pragma unroll
    for (int j = 0; j < NI; ++j)
#pragma unroll
      for (int r = 0; r < 4; ++r) acc[i][j][r] = 0.f;

  auto stage = [&](int bi, int k0) {
#pragma unroll
    for (int i = 0; i < 4; ++i) {
      const int c = w + i * 4;
      async_ld16(A + (size_t)(m0 + c * 8 + sr) * lda + k0 + ((sc ^ sr) * 8),
                 (void*)(As + bi * 8192 + c * 512));
    }
#pragma unroll
    for (int i = 0; i < BN / 32; ++i) {
      const int c = w + i * 4;
      async_ld16(B + (size_t)(n0 + c * 8 + sr) * ldb + k0 + ((sc ^ sr) * 8),
                 (void*)(Bs + bi * (BN * 64) + c * 512));
    }
  };

  const int nk = K >> 6;
  stage(0, 0);
  for (int t = 0; t < nk; ++t) {
    if (t + 1 < nk) {
      stage((t + 1) & 1, (t + 1) * 64);
      if (BN == 64) asm volatile("s_waitcnt vmcnt(6)" ::: "memory");
      else          asm volatile("s_waitcnt vmcnt(8)" ::: "memory");
    } else {
      asm volatile("s_waitcnt vmcnt(0)" ::: "memory");
    }
    __builtin_amdgcn_s_barrier();
    __builtin_amdgcn_sched_barrier(0);

    const __bf16* Ac = As + (t & 1) * 8192;
    const __bf16* Bc = Bs + (t & 1) * (BN * 64);
#pragma unroll
    for (int ks = 0; ks < 2; ++ks) {
      v8bf a[4], b[NI];
#pragma unroll
      for (int mi = 0; mi < 4; ++mi)
        a[mi] = *reinterpret_cast<const v8bf*>(
            Ac + (wr + mi * 16 + fr) * 64 + (((ks * 4 + fq) ^ (fr & 7)) * 8));
#pragma unroll
      for (int ni = 0; ni < NI; ++ni)
        b[ni] = *reinterpret_cast<const v8bf*>(
            Bc + (wc + ni * 16 + fr) * 64 + (((ks * 4 + fq) ^ (fr & 7)) * 8));
      __builtin_amdgcn_s_setprio(1);
#pragma unroll
      for (int mi = 0; mi < 4; ++mi)
#pragma unroll
        for (int ni = 0; ni < NI; ++ni)
          acc[mi][ni] = __builtin_amdgcn_mfma_f32_16x16x32_bf16(a[mi], b[ni], acc[mi][ni], 0, 0, 0);
      __builtin_amdgcn_s_setprio(0);
    }
    __builtin_amdgcn_sched_barrier(0);
    __builtin_amdgcn_s_barrier();
  }

#pragma unroll
  for (int mi = 0; mi < 4; ++mi)
#pragma unroll
    for (int ni = 0; ni < NI; ++ni)
#pragma unroll
      for (int r = 0; r < 4; ++r) {
        const int row = m0 + wr + mi * 16 + fq * 4 + r;
        const int col = n0 + wc + ni * 16 + fr;
        const float v = acc[mi][ni][r];
        if (OUTF32) {
          reinterpret_cast<float*>(C)[(size_t)row * ldc + col] = v + bias[col];
        } else {
          reinterpret_cast<__bf16*>(C)[(size_t)row * ldc + col] = (__bf16)v;
        }
      }
}

// merged projection, 128x64 tiles, dbuf (byte-identical to r17/r20)
__global__ __launch_bounds__(256) void proj_kernel(
    const __bf16* __restrict__ xb, const __bf16* __restrict__ w3,
    const __bf16* __restrict__ wvb, __bf16* __restrict__ qgk, __bf16* __restrict__ vt) {
  __shared__ __bf16 As[2 * 128 * 64];
  __shared__ __bf16 Bs[2 * 64 * 64];
  const int bid = blockIdx.x;
  if (bid < 1536) {
    gemm_tile<false, 64>(xb, w3, (void*)qgk, nullptr, 1024, 1024, 1024, 3072,
                         (bid / 48) * 128, (bid % 48) * 64, As, Bs);
  } else {
    const int t = bid - 1536;
    gemm_tile<false, 64>(wvb, xb, (void*)vt, nullptr, 1024, 1024, 1024, 4096,
                         (t >> 6) * 128, (t & 63) * 64, As, Bs);
  }
}

// ---------------- 64x64 out-GEMM tile (byte-identical to r18-r21) ----------------
__global__ __launch_bounds__(256) void gemm_out_kernel(
    const __bf16* __restrict__ A, const __bf16* __restrict__ B,
    float* __restrict__ C, const float* __restrict__ bias) {
  __shared__ __bf16 As[64 * 64];
  __shared__ __bf16 Bs[64 * 64];
  const int tid  = threadIdx.x;
  const int w    = tid >> 6;
  const int lane = tid & 63;
  const int fr   = lane & 15;
  const int fq   = lane >> 4;
  const int sr   = lane >> 3;
  const int sc   = lane & 7;
  const int m0 = blockIdx.y * 64, n0 = blockIdx.x * 64;
  const int wr = (w >> 1) * 32, wc = (w & 1) * 32;

  v4f acc[2][2];
#pragma unroll
  for (int i = 0; i < 2; ++i)
#pragma unroll
    for (int j = 0; j < 2; ++j)
#pragma unroll
      for (int r = 0; r < 4; ++r) acc[i][j][r] = 0.f;

  for (int k0 = 0; k0 < 1024; k0 += 64) {
#pragma unroll
    for (int i = 0; i < 2; ++i) {
      const int c = w + i * 4;
      async_ld16(A + (size_t)(m0 + c * 8 + sr) * 1024 + k0 + ((sc ^ sr) * 8),
                 (void*)(As + c * 512));
      async_ld16(B + (size_t)(n0 + c * 8 + sr) * 1024 + k0 + ((sc ^ sr) * 8),
                 (void*)(Bs + c * 512));
    }
    __syncthreads();

#pragma unroll
    for (int ks = 0; ks < 2; ++ks) {
      v8bf a[2], b[2];
#pragma unroll
      for (int mi = 0; mi < 2; ++mi)
        a[mi] = *reinterpret_cast<const v8bf*>(
            As + (wr + mi * 16 + fr) * 64 + (((ks * 4 + fq) ^ (fr & 7)) * 8));
#pragma unroll
      for (int ni = 0; ni < 2; ++ni)
        b[ni] = *reinterpret_cast<const v8bf*>(
            Bs + (wc + ni * 16 + fr) * 64 + (((ks * 4 + fq) ^ (fr & 7)) * 8));
      __builtin_amdgcn_s_setprio(1);
#pragma unroll
      for (int mi = 0; mi < 2; ++mi)
#pragma unroll
        for (int ni = 0; ni < 2; ++ni)
          acc[mi][ni] = __builtin_amdgcn_mfma_f32_16x16x32_bf16(a[mi], b[ni], acc[mi][ni], 0, 0, 0);
      __builtin_amdgcn_s_setprio(0);
    }
    __syncthreads();
  }

#pragma unroll
  for (int mi = 0; mi < 2; ++mi)
#pragma unroll
    for (int ni = 0; ni < 2; ++ni)
#pragma unroll
      for (int r = 0; r < 4; ++r) {
        const int row = m0 + wr + mi * 16 + fq * 4 + r;
        const int col = n0 + wc + ni * 16 + fr;
        C[(size_t)row * 1024 + col] = acc[mi][ni][r] + bias[col];
      }
}

// ---------------- flash attention: 4-wave blocks, K in LDS, V in regs ----------------
// (byte-identical to rounds 12-21 — deterministic, absmax 0.0039, steady ~29 us)
__global__ __launch_bounds__(256, 4) void attn_kernel(
    const __bf16* __restrict__ QGK, const __bf16* __restrict__ VT,
    __bf16* __restrict__ CTX) {
  constexpr int LD = 3072, L = 2048;
  __shared__ __align__(16) char lds[37888];
  const int w = threadIdx.x >> 6, lane = threadIdx.x & 63;
  const int fr = lane & 15, fq = lane >> 4;
  const int tl = w >> 1, hf = w & 1;
  const int u = blockIdx.x >> 8, v = blockIdx.x & 255;
  const int k = v >> 5;
  const int g = (u == 0) ? k : (u == 1) ? 15 - k : (u == 2) ? 16 + k : 31 - k;
  const int bh = v & 31;
  const int b = bh >> 4, h = bh & 15, hb = h * 64;
  const int qt = 2 * g + tl, q0 = qt * 32, nkt = g + 1;
  const __bf16* base  = QGK + (size_t)b * L * LD;
  const __bf16* vbase = VT + (size_t)hb * 4096 + (size_t)b * L;
  __bf16* pw = (__bf16*)(lds + 16384 + w * 2560);

  v8bf onev;
#pragma unroll
  for (int i = 0; i < 8; ++i) onev[i] = (__bf16)1.0f;

  v8bf qf[2][2];
#pragma unroll
  for (int mi = 0; mi < 2; ++mi)
#pragma unroll
    for (int ks = 0; ks < 2; ++ks)
      qf[mi][ks] = *reinterpret_cast<const v8bf*>(
          base + (size_t)(q0 + mi * 16 + fr) * LD + hb + ks * 32 + fq * 8);

  v4f cacc[2][4], csum[2];
#pragma unroll
  for (int mi = 0; mi < 2; ++mi) {
#pragma unroll
    for (int r = 0; r < 4; ++r) csum[mi][r] = 0.f;
#pragma unroll
    for (int nf = 0; nf < 4; ++nf)
#pragma unroll
      for (int r = 0; r < 4; ++r) cacc[mi][nf][r] = 0.f;
  }

  auto stage = [&](int bi, int k0s) {
    char* bf_ = (char*)lds + bi * 8192;
#pragma unroll
    for (int i = 0; i < 2; ++i) {
      const int slot = i * 256 + w * 64 + lane;
      const int r = slot >> 3;
      const int cc = ((slot & 7) ^ (r & 7)) * 8;
      async_ld16(base + (size_t)(k0s + r) * LD + 2048 + hb + cc,
                 bf_ + (i * 256 + w * 64) * 16);
    }
  };

  stage(0, 0);
  __syncthreads();
  for (int kt = 0; kt < nkt; ++kt) {
    const int k0 = kt * 64;
    const bool last = (kt == nkt - 1);
    v8bf vf[4];
#pragma unroll
    for (int nf = 0; nf < 4; ++nf)
      vf[nf] = *reinterpret_cast<const v8bf*>(
          vbase + (size_t)(nf * 16 + fr) * 4096 + k0 + hf * 32 + fq * 8);
    if (!last) stage((kt + 1) & 1, k0 + 64);

    if (!(last && tl == 0 && hf == 1)) {
      const __bf16* Kt = (const __bf16*)(lds + (kt & 1) * 8192);
      v8bf kf[2][2];
#pragma unroll
      for (int ks = 0; ks < 2; ++ks)
#pragma unroll
        for (int nj = 0; nj < 2; ++nj)
          kf[ks][nj] = *reinterpret_cast<const v8bf*>(
              Kt + (hf * 32 + nj * 16 + fr) * 64 + (((ks * 4 + fq) ^ (fr & 7)) * 8));

      v4f s[2][2];
#pragma unroll
      for (int mi = 0; mi < 2; ++mi)
#pragma unroll
        for (int nj = 0; nj < 2; ++nj)
#pragma unroll
          for (int r = 0; r < 4; ++r) s[mi][nj][r] = 0.f;
      __builtin_amdgcn_s_setprio(1);
#pragma unroll
      for (int ks = 0; ks < 2; ++ks)
#pragma unroll
        for (int mi = 0; mi < 2; ++mi)
#pragma unroll
          for (int nj = 0; nj < 2; ++nj)
            s[mi][nj] = __builtin_amdgcn_mfma_f32_16x16x32_bf16(
                kf[ks][nj], qf[mi][ks], s[mi][nj], 0, 0, 0);
      __builtin_amdgcn_s_setprio(0);

      const bool mask = last && (hf == tl);
#pragma unroll
      for (int mi = 0; mi < 2; ++mi) {
        const int qrow = q0 + mi * 16 + fr;
#pragma unroll
        for (int nj = 0; nj < 2; ++nj) {
          const int kvb = k0 + hf * 32 + nj * 16 + fq * 4;
          v4bf pk;
#pragma unroll
          for (int r = 0; r < 4; ++r) {
            float sv = s[mi][nj][r];
            if (mask && (kvb + r > qrow)) sv = -__builtin_inff();
            pk[r] = (__bf16)fexp2(sv - FIXMAX);
          }
          *reinterpret_cast<v4bf*>(pw + (mi * 16 + fr) * 40 + nj * 16 + fq * 4) = pk;
        }
      }

      v8bf pa[2];
#pragma unroll
      for (int mi = 0; mi < 2; ++mi)
        pa[mi] = *reinterpret_cast<const v8bf*>(pw + (mi * 16 + fr) * 40 + fq * 8);
      __builtin_amdgcn_s_setprio(1);
#pragma unroll
      for (int mi = 0; mi < 2; ++mi)
        csum[mi] = __builtin_amdgcn_mfma_f32_16x16x32_bf16(pa[mi], onev, csum[mi], 0, 0, 0);
#pragma unroll
      for (int nf = 0; nf < 4; ++nf)
#pragma unroll
        for (int mi = 0; mi < 2; ++mi)
          cacc[mi][nf] = __builtin_amdgcn_mfma_f32_16x16x32_bf16(pa[mi], vf[nf], cacc[mi][nf], 0, 0, 0);
      __builtin_amdgcn_s_setprio(0);
    }
    __syncthreads();
  }

  float* comb = (float*)(lds + 16384);
  float* slot = comb + (tl * 64 + lane) * 41;
  if (hf == 1) {
#pragma unroll
    for (int mi = 0; mi < 2; ++mi) {
#pragma unroll
      for (int nf = 0; nf < 4; ++nf)
#pragma unroll
        for (int r = 0; r < 4; ++r) slot[mi * 16 + nf * 4 + r] = cacc[mi][nf][r];
#pragma unroll
      for (int r = 0; r < 4; ++r) slot[32 + mi * 4 + r] = csum[mi][r];
    }
  }
  __syncthreads();
  if (hf == 0) {
#pragma unroll
    for (int mi = 0; mi < 2; ++mi) {
#pragma unroll
      for (int nf = 0; nf < 4; ++nf)
#pragma unroll
        for (int r = 0; r < 4; ++r) cacc[mi][nf][r] += slot[mi * 16 + nf * 4 + r];
#pragma unroll
      for (int r = 0; r < 4; ++r) csum[mi][r] += slot[32 + mi * 4 + r];
    }
#pragma unroll
    for (int mi = 0; mi < 2; ++mi)
#pragma unroll
      for (int r = 0; r < 4; ++r) {
        const int grow = q0 + mi * 16 + fq * 4 + r;
        const float rl = 1.f / csum[mi][r];
#pragma unroll
        for (int nf = 0; nf < 4; ++nf) {
          const int col = hb + nf * 16 + fr;
          float vv = cacc[mi][nf][r] * rl;
          const float gt = (float)base[(size_t)grow * LD + 1024 + col];
          vv *= 1.f / (1.f + fexp2(-gt * LOG2E));
          CTX[((size_t)b * L + grow) * 1024 + col] = (__bf16)vv;
        }
      }
  }
}

extern "C" void kernel_launch(void* const* d_in, const int* in_sizes, int n_in,
                              void* d_out, int out_size, void* d_ws, size_t ws_size,
                              hipStream_t stream) {
  const float* x  = (const float*)d_in[0];
  const float* Wq = (const float*)d_in[1];
  const float* Wg = (const float*)d_in[2];
  const float* Wk = (const float*)d_in[3];
  const float* Wv = (const float*)d_in[4];
  const float* Wo = (const float*)d_in[5];
  const float* bo = (const float*)d_in[6];

  char* ws = (char*)d_ws;
  __bf16* xb  = (__bf16*)(ws);                  //  8 MB  [4096,1024]
  __bf16* w3  = (__bf16*)(ws + (8u  << 20));    //  6 MB  [3072,1024]
  __bf16* wvb = (__bf16*)(ws + (14u << 20));    //  2 MB
  __bf16* wob = (__bf16*)(ws + (16u << 20));    //  2 MB
  __bf16* qgk = (__bf16*)(ws + (18u << 20));    // 24 MB  [4096,3072]
  __bf16* vt  = (__bf16*)(ws + (42u << 20));    //  8 MB  [1024,4096]
  __bf16* ctx = (__bf16*)(ws + (50u << 20));    //  8 MB  [4096,1024]

  cvt_all_kernel<<<dim3(4608), dim3(256), 0, stream>>>(x, Wq, Wg, Wk, Wv, Wo,
                                                       xb, w3, wvb, wob);

  // QGK (1536 blocks) + VT (512 blocks) in one dispatch; 128x64 tiles, dbuf
  proj_kernel<<<dim3(2048), dim3(256), 0, stream>>>(xb, w3, wvb, qgk, vt);

  // flash attention + gate: 1024 blocks = exact residency (4/CU)
  attn_kernel<<<dim3(1024), dim3(256), 0, stream>>>(qgk, vt, ctx);

  // out = ctx @ Wo^T + bo : 64x64 tiles -> 1024 blocks (4/CU)
  gemm_out_kernel<<<dim3(16, 64), dim3(256), 0, stream>>>(ctx, wob, (float*)d_out, bo);
}